// Round 4
// baseline (789.804 us; speedup 1.0000x reference)
//
#include <hip/hip_runtime.h>
#include <hip/hip_bf16.h>
#include <stdint.h>

#define B_ROWS 16384
#define DIM 2048
#define BK 64
#define NT 96        // 3 segments x 32 K-tiles
#define NPIECE 384   // NT*4

typedef float f32x4 __attribute__((ext_vector_type(4)));
typedef short bf16x8 __attribute__((ext_vector_type(8)));
using u16 = unsigned short;
using u32 = unsigned int;

__device__ __forceinline__ u32 pack_bf2(float a, float b) {
  __hip_bfloat162 t = __float22bfloat162_rn(float2{a, b});
  union { __hip_bfloat162 b2; u32 u; } cv;
  cv.b2 = t;
  return cv.u;
}

__device__ __forceinline__ u16 f2bf_rne(float f) {
  union { float f; u32 u; } v;
  v.f = f;
  u32 u = v.u;
  u32 r = u + 0x7FFFu + ((u >> 16) & 1u);
  return (u16)(r >> 16);
}

__device__ __forceinline__ void gload16(const void* g, void* l) {
  __builtin_amdgcn_global_load_lds(
      (const __attribute__((address_space(1))) u32*)g,
      (__attribute__((address_space(3))) u32*)l, 16, 0, 0);
}

// ---- prep: flags (fp64 last-col dot) + x->bf16 + masked hF/hI (no atomics) --
__global__ __launch_bounds__(256) void k_prep(
    const float* __restrict__ x, const float* __restrict__ h,
    const float* __restrict__ W_ih, int* __restrict__ flags,
    u16* __restrict__ xb, u16* __restrict__ hF, u16* __restrict__ hI) {
  int row = blockIdx.x * 4 + (threadIdx.x >> 6);
  int lane = threadIdx.x & 63;
  const float* xr = x + (size_t)row * DIM;
  const float* hr = h + (size_t)row * DIM;
  const float* wr = W_ih + (size_t)(DIM - 1) * DIM;
  u16* xbr = xb + (size_t)row * DIM;
  double s = 0.0;
  u32 hp[16];
#pragma unroll
  for (int i = 0; i < 8; ++i) {
    int idx = (i * 64 + lane) * 4;
    f32x4 xv = *(const f32x4*)(xr + idx);
    f32x4 wv = *(const f32x4*)(wr + idx);
    f32x4 hv = *(const f32x4*)(hr + idx);
    s += (double)xv.x * wv.x + (double)xv.y * wv.y +
         (double)xv.z * wv.z + (double)xv.w * wv.w;
    *(uint2*)(xbr + idx) = uint2{pack_bf2(xv.x, xv.y), pack_bf2(xv.z, xv.w)};
    hp[2 * i] = pack_bf2(hv.x, hv.y);
    hp[2 * i + 1] = pack_bf2(hv.z, hv.w);
  }
#pragma unroll
  for (int off = 32; off > 0; off >>= 1) s += __shfl_xor(s, off);
  float hl = hr[DIM - 1];
  int f = (s < -1.0) ? 2 : (hl > 0.f ? 0 : (hl < 0.f ? 1 : 3));
  if (lane == 0) flags[row] = f;
  uint2 z{0u, 0u};
  u16* hFr = hF + (size_t)row * DIM;
  u16* hIr = hI + (size_t)row * DIM;
#pragma unroll
  for (int i = 0; i < 8; ++i) {
    int idx = (i * 64 + lane) * 4;
    uint2 p{hp[2 * i], hp[2 * i + 1]};
    *(uint2*)(hFr + idx) = (f == 0) ? p : z;
    *(uint2*)(hIr + idx) = (f == 1) ? p : z;
  }
}

// ---- flags only (fallback path) --------------------------------------------
__global__ __launch_bounds__(256) void k_flags_fb(
    const float* __restrict__ x, const float* __restrict__ h,
    const float* __restrict__ W_ih, int* __restrict__ flags) {
  int row = blockIdx.x * 4 + (threadIdx.x >> 6);
  int lane = threadIdx.x & 63;
  const float* xr = x + (size_t)row * DIM;
  const float* wr = W_ih + (size_t)(DIM - 1) * DIM;
  double s = 0.0;
#pragma unroll
  for (int i = 0; i < 8; ++i) {
    int idx = (i * 64 + lane) * 4;
    f32x4 xv = *(const f32x4*)(xr + idx);
    f32x4 wv = *(const f32x4*)(wr + idx);
    s += (double)xv.x * wv.x + (double)xv.y * wv.y +
         (double)xv.z * wv.z + (double)xv.w * wv.w;
  }
#pragma unroll
  for (int off = 32; off > 0; off >>= 1) s += __shfl_xor(s, off);
  if (lane == 0) {
    float hl = h[(size_t)row * DIM + (DIM - 1)];
    flags[row] = (s < -1.0) ? 2 : (hl > 0.f ? 0 : (hl < 0.f ? 1 : 3));
  }
}

// ---- convert W_ih ([N][K] already) f32 -> bf16 ------------------------------
__global__ __launch_bounds__(256) void k_convert(const float* __restrict__ src,
                                                 u16* __restrict__ dst) {
  size_t i = ((size_t)blockIdx.x * 256 + threadIdx.x) * 4;
  f32x4 v = *(const f32x4*)(src + i);
  *(uint2*)(dst + i) = uint2{pack_bf2(v.x, v.y), pack_bf2(v.z, v.w)};
}

// ---- transpose+convert [K][N] f32 -> [N][K] bf16 ----------------------------
__global__ __launch_bounds__(256) void k_transpose(const float* __restrict__ src,
                                                   u16* __restrict__ dst) {
  __shared__ float tile[32][33];
  int k0 = blockIdx.x * 32;
  int n0 = blockIdx.y * 32;
  int tx = threadIdx.x & 31;
  int ty = threadIdx.x >> 5;
#pragma unroll
  for (int i = 0; i < 4; ++i)
    tile[ty + 8 * i][tx] = src[(size_t)(k0 + ty + 8 * i) * DIM + n0 + tx];
  __syncthreads();
#pragma unroll
  for (int i = 0; i < 4; ++i)
    dst[(size_t)(n0 + ty + 8 * i) * DIM + k0 + tx] = f2bf_rne(tile[tx][ty + 8 * i]);
}

// ---- 8-phase 256^2 3-segment GEMM (T3+T4+T5), K-half pieces, no swizzle -----
// LDS: 2 buf x 4 pieces x 16KB = 128KB. Piece = [256 rows][32 K] bf16.
// Phase (kk,mh): 16 MFMA; stage 1 piece/phase at lookahead 6; vmcnt(8) at
// phases 2,4 only. Liveness: k0 regions dead after phase 2; staged pieces
// t+2.k0 land there. lgkmcnt(0)+end-barrier per phase orders DMA vs ds_read.
__global__ __launch_bounds__(512, 2) void k_gemm8(
    const u16* __restrict__ xb, const u16* __restrict__ hF,
    const u16* __restrict__ hI, const u16* __restrict__ Wih,
    const u16* __restrict__ WhhT, const u16* __restrict__ WinvT,
    const int* __restrict__ flags, const float* __restrict__ h,
    float* __restrict__ out) {
  __shared__ __attribute__((aligned(128))) char smem[131072];

  int o = blockIdx.x;
  int swz = (o & 7) * 64 + (o >> 3);     // 512 blocks, 8 XCDs, bijective
  int brow = (swz >> 3) * 256;
  int bcol = (swz & 7) * 256;

  int t = threadIdx.x;
  int lane = t & 63;
  int wave = t >> 6;
  int wr = wave >> 2;                    // 0..1
  int wc = wave & 3;                     // 0..3

  // staging lanes: chunk = (wave*2+i)*64 + lane; row = chunk>>2; k16 = lane&3
  int srow0 = (wave * 2 + 0) * 16 + (lane >> 2);
  int srow1 = (wave * 2 + 1) * 16 + (lane >> 2);
  int sk16 = lane & 3;

  auto stage = [&](int P) {
    if (P >= NPIECE) P -= NPIECE;
    int Tp = P >> 2;
    int c = P & 3;                       // 0:Ak0 1:Bk0 2:Ak1 3:Bk1
    int seg = Tp >> 5;
    int kt = Tp & 31;
    const u16* Ab = seg == 0 ? xb : (seg == 1 ? hF : hI);
    const u16* Bb = seg == 0 ? Wih : (seg == 1 ? WhhT : WinvT);
    const char* base;
    int r0;
    if (c & 1) { base = (const char*)Bb; r0 = bcol; }
    else       { base = (const char*)Ab; r0 = brow; }
    size_t gk = (size_t)kt * 128 + (size_t)(c >> 1) * 64 + (size_t)sk16 * 16;
    char* ldst = smem + ((Tp & 1) << 16) + (c << 14) + wave * 2048;
    gload16(base + (size_t)(r0 + srow0) * (DIM * 2) + gk, ldst);
    gload16(base + (size_t)(r0 + srow1) * (DIM * 2) + gk, ldst + 1024);
  };

  f32x4 acc[8][4] = {};

  // fragment addressing (within a piece): row*64 + (lane>>4)*16
  int arow = wr * 128 + (lane & 15);
  int brf = wc * 64 + (lane & 15);
  int c16 = (lane >> 4) * 16;

  // prologue: stage pieces 0..5; pieces 0,1 complete before first reads
  for (int p = 0; p < 6; ++p) stage(p);
  asm volatile("s_waitcnt vmcnt(8)" ::: "memory");
  __builtin_amdgcn_s_barrier();

  bf16x8 aF[4], bF[4];

#define PHASE(KK, MH, STP, DOVM)                                              \
  {                                                                           \
    char* ab = smem + buf + (KK)*32768 + (arow + (MH)*64) * 64 + c16;         \
    aF[0] = *(const bf16x8*)(ab);                                             \
    aF[1] = *(const bf16x8*)(ab + 1024);                                      \
    aF[2] = *(const bf16x8*)(ab + 2048);                                      \
    aF[3] = *(const bf16x8*)(ab + 3072);                                      \
    if ((MH) == 0) {                                                          \
      char* bb = smem + buf + (KK)*32768 + 16384 + brf * 64 + c16;            \
      bF[0] = *(const bf16x8*)(bb);                                           \
      bF[1] = *(const bf16x8*)(bb + 1024);                                    \
      bF[2] = *(const bf16x8*)(bb + 2048);                                    \
      bF[3] = *(const bf16x8*)(bb + 3072);                                    \
    }                                                                         \
    stage(STP);                                                               \
    if (DOVM) asm volatile("s_waitcnt vmcnt(8)" ::: "memory");                \
    __builtin_amdgcn_s_barrier();                                             \
    asm volatile("s_waitcnt lgkmcnt(0)" ::: "memory");                        \
    __builtin_amdgcn_sched_barrier(0);                                        \
    __builtin_amdgcn_s_setprio(1);                                            \
    _Pragma("unroll") for (int m = 0; m < 4; ++m)                             \
        _Pragma("unroll") for (int n = 0; n < 4; ++n)                         \
            acc[(MH)*4 + m][n] = __builtin_amdgcn_mfma_f32_16x16x32_bf16(     \
                aF[m], bF[n], acc[(MH)*4 + m][n], 0, 0, 0);                   \
    __builtin_amdgcn_s_setprio(0);                                            \
    __builtin_amdgcn_s_barrier();                                             \
  }

#pragma unroll 2
  for (int T = 0; T < NT; ++T) {
    const int buf = (T & 1) << 16;
    const int sb = 4 * T + 6;
    PHASE(0, 0, sb + 0, false)
    PHASE(0, 1, sb + 1, true)
    PHASE(1, 0, sb + 2, false)
    PHASE(1, 1, sb + 3, true)
  }
#undef PHASE

  // epilogue: C mapping col=lane&15, row=(lane>>4)*4+j (proven R2 layout)
#pragma unroll
  for (int mi = 0; mi < 8; ++mi) {
    int rbase = brow + wr * 128 + (mi >> 2) * 64 + (mi & 3) * 16 + (lane >> 4) * 4;
#pragma unroll
    for (int j = 0; j < 4; ++j) {
      int row = rbase + j;
      bool pass = (flags[row] == 2);
#pragma unroll
      for (int n = 0; n < 4; ++n) {
        int col = bcol + wc * 64 + n * 16 + (lane & 15);
        float v = acc[mi][n][j];
        if (pass) v += h[(size_t)row * DIM + col];
        out[(size_t)row * DIM + col] = v;
      }
    }
  }
}

// ---- fallback (ws too small): R1 reg-staged 3-segment masked GEMM -----------
#define BM 128
#define BN 128
__global__ __launch_bounds__(256, 2) void k_gemm_fb(
    const float* __restrict__ x, const float* __restrict__ h,
    const u16* __restrict__ Wih, const u16* __restrict__ WhhT,
    const u16* __restrict__ WinvT, const int* __restrict__ flags,
    float* __restrict__ out) {
  __shared__ char smem[(BM + BN) * BK * 2];
  char* sA = smem;
  char* sB = smem + BM * BK * 2;

  int o = blockIdx.x;
  int swz = (o & 7) * ((int)gridDim.x >> 3) + (o >> 3);
  int brow = (swz >> 4) * BM;
  int bcol = (swz & 15) * BN;

  int t = threadIdx.x;
  int lane = t & 63;
  int wave = t >> 6;
  int wrow = (wave >> 1) * 64;
  int wcol = (wave & 1) * 64;

  f32x4 acc[4][4] = {};
  int sc = t & 15;
  int sr0 = t >> 4;

  int aOff[4][2], bOff[4][2];
#pragma unroll
  for (int m = 0; m < 4; ++m)
#pragma unroll
    for (int kk = 0; kk < 2; ++kk) {
      int ar = wrow + m * 16 + (lane & 15);
      aOff[m][kk] = ar * (BK * 2) + ((kk * 64 + (lane >> 4) * 16) ^ ((ar & 7) << 4));
      int br = wcol + m * 16 + (lane & 15);
      bOff[m][kk] = br * (BK * 2) + ((kk * 64 + (lane >> 4) * 16) ^ ((br & 7) << 4));
    }

#pragma unroll 1
  for (int seg = 0; seg < 3; ++seg) {
    const float* Asrc = (seg == 0) ? x : h;
    const u16* Bsrc = (seg == 0) ? Wih : (seg == 1) ? WhhT : WinvT;
    int want = seg - 1;

    float rmask[8];
#pragma unroll
    for (int i = 0; i < 8; ++i) {
      int r = sr0 + 16 * i;
      rmask[i] = (want < 0 || flags[brow + r] == want) ? 1.f : 0.f;
    }

#pragma unroll 1
    for (int k0 = 0; k0 < DIM; k0 += BK) {
      __syncthreads();
#pragma unroll
      for (int i = 0; i < 8; ++i) {
        int r = sr0 + 16 * i;
        f32x4 v = *(const f32x4*)(Asrc + (size_t)(brow + r) * DIM + k0 + sc * 4);
        float msk = rmask[i];
        int off = r * (BK * 2) + ((sc * 8) ^ ((r & 7) << 4));
        *(uint2*)(sA + off) =
            uint2{pack_bf2(v.x * msk, v.y * msk), pack_bf2(v.z * msk, v.w * msk)};
      }
#pragma unroll
      for (int i = 0; i < 4; ++i) {
        int ch = t + 256 * i;
        int r = ch >> 3;
        int c = ch & 7;
        uint4 v = *(const uint4*)(Bsrc + (size_t)(bcol + r) * DIM + k0 + c * 8);
        int off = r * (BK * 2) + ((c * 16) ^ ((r & 7) << 4));
        *(uint4*)(sB + off) = v;
      }
      __syncthreads();
      bf16x8 aF2[4][2], bF2[4][2];
#pragma unroll
      for (int m = 0; m < 4; ++m)
#pragma unroll
        for (int kk = 0; kk < 2; ++kk) {
          aF2[m][kk] = *(const bf16x8*)(sA + aOff[m][kk]);
          bF2[m][kk] = *(const bf16x8*)(sB + bOff[m][kk]);
        }
#pragma unroll
      for (int kk = 0; kk < 2; ++kk)
#pragma unroll
        for (int m = 0; m < 4; ++m)
#pragma unroll
          for (int n = 0; n < 4; ++n)
            acc[m][n] = __builtin_amdgcn_mfma_f32_16x16x32_bf16(
                aF2[m][kk], bF2[n][kk], acc[m][n], 0, 0, 0);
    }
  }

#pragma unroll
  for (int m = 0; m < 4; ++m) {
    int rbase = brow + wrow + m * 16 + (lane >> 4) * 4;
#pragma unroll
    for (int j = 0; j < 4; ++j) {
      int row = rbase + j;
      bool pass = (flags[row] == 2);
#pragma unroll
      for (int n = 0; n < 4; ++n) {
        int col = bcol + wcol + n * 16 + (lane & 15);
        float v = acc[m][n][j];
        if (pass) v += h[(size_t)row * DIM + col];
        out[(size_t)row * DIM + col] = v;
      }
    }
  }
}

extern "C" void kernel_launch(void* const* d_in, const int* in_sizes, int n_in,
                              void* d_out, int out_size, void* d_ws, size_t ws_size,
                              hipStream_t stream) {
  const float* x = (const float*)d_in[0];
  const float* h = (const float*)d_in[1];
  const float* W_ih = (const float*)d_in[2];
  const float* W_hh = (const float*)d_in[3];
  const float* W_inv = (const float*)d_in[4];
  float* out = (float*)d_out;

  char* ws = (char*)d_ws;
  int* flags = (int*)ws;                               // 64 KB
  u16* WihB = (u16*)(ws + (64 << 10));                 // 8 MB
  u16* WhhT = WihB + (size_t)DIM * DIM;                // 8 MB
  u16* WinvT = WhhT + (size_t)DIM * DIM;               // 8 MB
  u16* xb = WinvT + (size_t)DIM * DIM;                 // 64 MB
  u16* hF = xb + (size_t)B_ROWS * DIM;                 // 64 MB
  u16* hI = hF + (size_t)B_ROWS * DIM;                 // 64 MB
  size_t need = (size_t)(64 << 10) + 3ull * DIM * DIM * 2 + 3ull * B_ROWS * DIM * 2;

  k_convert<<<(DIM * DIM / 4) / 256, 256, 0, stream>>>(W_ih, WihB);
  k_transpose<<<dim3(DIM / 32, DIM / 32), 256, 0, stream>>>(W_hh, WhhT);
  k_transpose<<<dim3(DIM / 32, DIM / 32), 256, 0, stream>>>(W_inv, WinvT);

  if (ws_size >= need) {
    k_prep<<<B_ROWS / 4, 256, 0, stream>>>(x, h, W_ih, flags, xb, hF, hI);
    k_gemm8<<<(B_ROWS / 256) * (DIM / 256), 512, 0, stream>>>(
        xb, hF, hI, WihB, WhhT, WinvT, flags, h, out);
  } else {
    k_flags_fb<<<B_ROWS / 4, 256, 0, stream>>>(x, h, W_ih, flags);
    k_gemm_fb<<<(B_ROWS / BM) * (DIM / BN), 256, 0, stream>>>(x, h, WihB, WhhT,
                                                              WinvT, flags, out);
  }
}

// Round 5
// 506.465 us; speedup vs baseline: 1.5594x; 1.5594x over previous
//
#include <hip/hip_runtime.h>
#include <hip/hip_bf16.h>
#include <stdint.h>

#define B_ROWS 16384
#define DIM 2048
#define BK 64
#define NT 96        // 3 segments x 32 K-tiles

typedef float f32x4 __attribute__((ext_vector_type(4)));
typedef short bf16x8 __attribute__((ext_vector_type(8)));
using u16 = unsigned short;
using u32 = unsigned int;

__device__ __forceinline__ u32 pack_bf2(float a, float b) {
  __hip_bfloat162 t = __float22bfloat162_rn(float2{a, b});
  union { __hip_bfloat162 b2; u32 u; } cv;
  cv.b2 = t;
  return cv.u;
}

__device__ __forceinline__ u16 f2bf_rne(float f) {
  union { float f; u32 u; } v;
  v.f = f;
  u32 u = v.u;
  u32 r = u + 0x7FFFu + ((u >> 16) & 1u);
  return (u16)(r >> 16);
}

__device__ __forceinline__ void gload16(const void* g, void* l) {
  __builtin_amdgcn_global_load_lds(
      (const __attribute__((address_space(1))) u32*)g,
      (__attribute__((address_space(3))) u32*)l, 16, 0, 0);
}

// ---- prep: flags (fp64 last-col dot) + x->bf16 + masked hF/hI --------------
__global__ __launch_bounds__(256) void k_prep(
    const float* __restrict__ x, const float* __restrict__ h,
    const float* __restrict__ W_ih, int* __restrict__ flags,
    u16* __restrict__ xb, u16* __restrict__ hF, u16* __restrict__ hI) {
  int row = blockIdx.x * 4 + (threadIdx.x >> 6);
  int lane = threadIdx.x & 63;
  const float* xr = x + (size_t)row * DIM;
  const float* hr = h + (size_t)row * DIM;
  const float* wr = W_ih + (size_t)(DIM - 1) * DIM;
  u16* xbr = xb + (size_t)row * DIM;
  double s = 0.0;
  u32 hp[16];
#pragma unroll
  for (int i = 0; i < 8; ++i) {
    int idx = (i * 64 + lane) * 4;
    f32x4 xv = *(const f32x4*)(xr + idx);
    f32x4 wv = *(const f32x4*)(wr + idx);
    f32x4 hv = *(const f32x4*)(hr + idx);
    s += (double)xv.x * wv.x + (double)xv.y * wv.y +
         (double)xv.z * wv.z + (double)xv.w * wv.w;
    *(uint2*)(xbr + idx) = uint2{pack_bf2(xv.x, xv.y), pack_bf2(xv.z, xv.w)};
    hp[2 * i] = pack_bf2(hv.x, hv.y);
    hp[2 * i + 1] = pack_bf2(hv.z, hv.w);
  }
#pragma unroll
  for (int off = 32; off > 0; off >>= 1) s += __shfl_xor(s, off);
  float hl = hr[DIM - 1];
  int f = (s < -1.0) ? 2 : (hl > 0.f ? 0 : (hl < 0.f ? 1 : 3));
  if (lane == 0) flags[row] = f;
  uint2 z{0u, 0u};
  u16* hFr = hF + (size_t)row * DIM;
  u16* hIr = hI + (size_t)row * DIM;
#pragma unroll
  for (int i = 0; i < 8; ++i) {
    int idx = (i * 64 + lane) * 4;
    uint2 p{hp[2 * i], hp[2 * i + 1]};
    *(uint2*)(hFr + idx) = (f == 0) ? p : z;
    *(uint2*)(hIr + idx) = (f == 1) ? p : z;
  }
}

// ---- flags only (fallback path) --------------------------------------------
__global__ __launch_bounds__(256) void k_flags_fb(
    const float* __restrict__ x, const float* __restrict__ h,
    const float* __restrict__ W_ih, int* __restrict__ flags) {
  int row = blockIdx.x * 4 + (threadIdx.x >> 6);
  int lane = threadIdx.x & 63;
  const float* xr = x + (size_t)row * DIM;
  const float* wr = W_ih + (size_t)(DIM - 1) * DIM;
  double s = 0.0;
#pragma unroll
  for (int i = 0; i < 8; ++i) {
    int idx = (i * 64 + lane) * 4;
    f32x4 xv = *(const f32x4*)(xr + idx);
    f32x4 wv = *(const f32x4*)(wr + idx);
    s += (double)xv.x * wv.x + (double)xv.y * wv.y +
         (double)xv.z * wv.z + (double)xv.w * wv.w;
  }
#pragma unroll
  for (int off = 32; off > 0; off >>= 1) s += __shfl_xor(s, off);
  if (lane == 0) {
    float hl = h[(size_t)row * DIM + (DIM - 1)];
    flags[row] = (s < -1.0) ? 2 : (hl > 0.f ? 0 : (hl < 0.f ? 1 : 3));
  }
}

// ---- convert W_ih ([N][K] already) f32 -> bf16 ------------------------------
__global__ __launch_bounds__(256) void k_convert(const float* __restrict__ src,
                                                 u16* __restrict__ dst) {
  size_t i = ((size_t)blockIdx.x * 256 + threadIdx.x) * 4;
  f32x4 v = *(const f32x4*)(src + i);
  *(uint2*)(dst + i) = uint2{pack_bf2(v.x, v.y), pack_bf2(v.z, v.w)};
}

// ---- transpose+convert [K][N] f32 -> [N][K] bf16 ----------------------------
__global__ __launch_bounds__(256) void k_transpose(const float* __restrict__ src,
                                                   u16* __restrict__ dst) {
  __shared__ float tile[32][33];
  int k0 = blockIdx.x * 32;
  int n0 = blockIdx.y * 32;
  int tx = threadIdx.x & 31;
  int ty = threadIdx.x >> 5;
#pragma unroll
  for (int i = 0; i < 4; ++i)
    tile[ty + 8 * i][tx] = src[(size_t)(k0 + ty + 8 * i) * DIM + n0 + tx];
  __syncthreads();
#pragma unroll
  for (int i = 0; i < 4; ++i)
    dst[(size_t)(n0 + ty + 8 * i) * DIM + k0 + tx] = f2bf_rne(tile[tx][ty + 8 * i]);
}

// ---- 256^2 4-phase/K-tile pipelined GEMM (T3+T4+T5), swizzled K-half slabs --
// LDS: 2 buf x {Ak0 16K | Bk0 16K | Ak1 16K | Bk1 16K} = 128 KB.
// Swizzle: LDS[row][c16] = G[row][c16 ^ ((row>>1)&3)] (pre-swizzled source;
// same XOR on read) -> b128 reads hit the 8-access/bank minimum.
// Stage map: p0:(t+1,A,k1) p1:(t+1,B,k1) p2:(t+2,A,k0) p3:(t+2,B,k0); every
// target region is dead behind a barrier. vmcnt(8) at p1/p3 end retires
// exactly the 2 slabs the next 2 phases read (5-phase latency cover).
__global__ __launch_bounds__(512, 2) void k_gemm8(
    const u16* __restrict__ xb, const u16* __restrict__ hF,
    const u16* __restrict__ hI, const u16* __restrict__ Wih,
    const u16* __restrict__ WhhT, const u16* __restrict__ WinvT,
    const int* __restrict__ flags, const float* __restrict__ h,
    float* __restrict__ out) {
  __shared__ __attribute__((aligned(128))) char smem[131072];

  int o = blockIdx.x;
  int swz = (o & 7) * 64 + (o >> 3);     // 512 blocks, 8 XCDs, bijective
  int brow = (swz >> 3) * 256;
  int bcol = (swz & 7) * 256;

  int t = threadIdx.x;
  int lane = t & 63;
  int wave = t >> 6;
  int wr = wave >> 2;                    // 0..1  (M half)
  int wc = wave & 3;                     // 0..3  (N quarter)

  // staging source-chunk swizzle: chunk = (lane&3) ^ ((lane>>3)&3)
  int sx16 = (((lane & 3) ^ ((lane >> 3) & 3)) << 4);
  // fragment read chunk swizzle: chunk = (lane>>4) ^ ((lane>>1)&3)
  int fA = (((lane >> 4) ^ ((lane >> 1) & 3)) << 4);
  int arowbase = wr * 128 + (lane & 15);
  int browbase = wc * 64 + (lane & 15);

  auto stage = [&](int T, int isB, int kk) {
    if (T >= NT) T -= NT;
    int seg = T >> 5;
    int kt = T & 31;
    const u16* mat = isB ? (seg == 0 ? Wih : seg == 1 ? WhhT : WinvT)
                         : (seg == 0 ? xb : seg == 1 ? hF : hI);
    int r0 = isB ? bcol : brow;
    size_t gb = (size_t)(r0 + wave * 32 + (lane >> 2)) * (DIM * 2) +
                (size_t)kt * 128 + (size_t)kk * 64 + (size_t)sx16;
    char* ldst = smem + ((T & 1) << 16) + kk * 32768 + isB * 16384 +
                 (wave * 32) * 64;
    gload16((const char*)mat + gb, ldst);
    gload16((const char*)mat + gb + (size_t)16 * (DIM * 2), ldst + 1024);
  };

  f32x4 acc[8][4] = {};
  bf16x8 aF[4], bF[4];

  // prologue: FIFO [(0,A,k0),(0,B,k0),(0,A,k1),(0,B,k1),(1,A,k0),(1,B,k0)]
  stage(0, 0, 0); stage(0, 1, 0); stage(0, 0, 1);
  stage(0, 1, 1); stage(1, 0, 0); stage(1, 1, 0);
  asm volatile("s_waitcnt vmcnt(8)" ::: "memory");
  __builtin_amdgcn_s_barrier();

#define PHASE(KK, MH, RDB, STT, STB, STKK, DOVM)                               \
  {                                                                            \
    const char* Ab_ = smem + buf + (KK) * 32768;                               \
    _Pragma("unroll") for (int m = 0; m < 4; ++m)                              \
        aF[m] = *(const bf16x8*)(Ab_ +                                         \
                                 (arowbase + (MH) * 64 + m * 16) * 64 + fA);   \
    if (RDB) {                                                                 \
      _Pragma("unroll") for (int n = 0; n < 4; ++n)                            \
          bF[n] = *(const bf16x8*)(Ab_ + 16384 +                               \
                                   (browbase + n * 16) * 64 + fA);             \
    }                                                                          \
    stage(STT, STB, STKK);                                                     \
    __builtin_amdgcn_s_barrier();                                              \
    asm volatile("s_waitcnt lgkmcnt(0)" ::: "memory");                         \
    __builtin_amdgcn_sched_barrier(0);                                         \
    __builtin_amdgcn_s_setprio(1);                                             \
    _Pragma("unroll") for (int m = 0; m < 4; ++m)                              \
        _Pragma("unroll") for (int n = 0; n < 4; ++n)                          \
            acc[(MH) * 4 + m][n] = __builtin_amdgcn_mfma_f32_16x16x32_bf16(    \
                aF[m], bF[n], acc[(MH) * 4 + m][n], 0, 0, 0);                  \
    __builtin_amdgcn_s_setprio(0);                                             \
    if (DOVM) asm volatile("s_waitcnt vmcnt(8)" ::: "memory");                 \
    __builtin_amdgcn_s_barrier();                                              \
  }

#pragma unroll 1
  for (int T = 0; T < NT; ++T) {
    const int buf = (T & 1) << 16;
    PHASE(0, 0, 1, T + 1, 0, 1, 0)   // read Ak0(mh0)+Bk0; stage (t+1,A,k1)
    PHASE(0, 1, 0, T + 1, 1, 1, 1)   // read Ak0(mh1);     stage (t+1,B,k1); vmcnt
    PHASE(1, 0, 1, T + 2, 0, 0, 0)   // read Ak1(mh0)+Bk1; stage (t+2,A,k0)
    PHASE(1, 1, 0, T + 2, 1, 0, 1)   // read Ak1(mh1);     stage (t+2,B,k0); vmcnt
  }
#undef PHASE
  asm volatile("s_waitcnt vmcnt(0)" ::: "memory");

  // epilogue: C mapping col=lane&15, row=(lane>>4)*4+j (R2-proven layout)
#pragma unroll
  for (int mi = 0; mi < 8; ++mi) {
    int rbase = brow + wr * 128 + (mi >> 2) * 64 + (mi & 3) * 16 + (lane >> 4) * 4;
#pragma unroll
    for (int j = 0; j < 4; ++j) {
      int row = rbase + j;
      bool pass = (flags[row] == 2);
#pragma unroll
      for (int n = 0; n < 4; ++n) {
        int col = bcol + wc * 64 + n * 16 + (lane & 15);
        float v = acc[mi][n][j];
        if (pass) v += h[(size_t)row * DIM + col];
        out[(size_t)row * DIM + col] = v;
      }
    }
  }
}

// ---- fallback (ws too small): R1 reg-staged 3-segment masked GEMM -----------
#define BM 128
#define BN 128
__global__ __launch_bounds__(256, 2) void k_gemm_fb(
    const float* __restrict__ x, const float* __restrict__ h,
    const u16* __restrict__ Wih, const u16* __restrict__ WhhT,
    const u16* __restrict__ WinvT, const int* __restrict__ flags,
    float* __restrict__ out) {
  __shared__ char smem[(BM + BN) * BK * 2];
  char* sA = smem;
  char* sB = smem + BM * BK * 2;

  int o = blockIdx.x;
  int swz = (o & 7) * ((int)gridDim.x >> 3) + (o >> 3);
  int brow = (swz >> 4) * BM;
  int bcol = (swz & 15) * BN;

  int t = threadIdx.x;
  int lane = t & 63;
  int wave = t >> 6;
  int wrow = (wave >> 1) * 64;
  int wcol = (wave & 1) * 64;

  f32x4 acc[4][4] = {};
  int sc = t & 15;
  int sr0 = t >> 4;

  int aOff[4][2], bOff[4][2];
#pragma unroll
  for (int m = 0; m < 4; ++m)
#pragma unroll
    for (int kk = 0; kk < 2; ++kk) {
      int ar = wrow + m * 16 + (lane & 15);
      aOff[m][kk] = ar * (BK * 2) + ((kk * 64 + (lane >> 4) * 16) ^ ((ar & 7) << 4));
      int br = wcol + m * 16 + (lane & 15);
      bOff[m][kk] = br * (BK * 2) + ((kk * 64 + (lane >> 4) * 16) ^ ((br & 7) << 4));
    }

#pragma unroll 1
  for (int seg = 0; seg < 3; ++seg) {
    const float* Asrc = (seg == 0) ? x : h;
    const u16* Bsrc = (seg == 0) ? Wih : (seg == 1) ? WhhT : WinvT;
    int want = seg - 1;

    float rmask[8];
#pragma unroll
    for (int i = 0; i < 8; ++i) {
      int r = sr0 + 16 * i;
      rmask[i] = (want < 0 || flags[brow + r] == want) ? 1.f : 0.f;
    }

#pragma unroll 1
    for (int k0 = 0; k0 < DIM; k0 += BK) {
      __syncthreads();
#pragma unroll
      for (int i = 0; i < 8; ++i) {
        int r = sr0 + 16 * i;
        f32x4 v = *(const f32x4*)(Asrc + (size_t)(brow + r) * DIM + k0 + sc * 4);
        float msk = rmask[i];
        int off = r * (BK * 2) + ((sc * 8) ^ ((r & 7) << 4));
        *(uint2*)(sA + off) =
            uint2{pack_bf2(v.x * msk, v.y * msk), pack_bf2(v.z * msk, v.w * msk)};
      }
#pragma unroll
      for (int i = 0; i < 4; ++i) {
        int ch = t + 256 * i;
        int r = ch >> 3;
        int c = ch & 7;
        uint4 v = *(const uint4*)(Bsrc + (size_t)(bcol + r) * DIM + k0 + c * 8);
        int off = r * (BK * 2) + ((c * 16) ^ ((r & 7) << 4));
        *(uint4*)(sB + off) = v;
      }
      __syncthreads();
      bf16x8 aF2[4][2], bF2[4][2];
#pragma unroll
      for (int m = 0; m < 4; ++m)
#pragma unroll
        for (int kk = 0; kk < 2; ++kk) {
          aF2[m][kk] = *(const bf16x8*)(sA + aOff[m][kk]);
          bF2[m][kk] = *(const bf16x8*)(sB + bOff[m][kk]);
        }
#pragma unroll
      for (int kk = 0; kk < 2; ++kk)
#pragma unroll
        for (int m = 0; m < 4; ++m)
#pragma unroll
          for (int n = 0; n < 4; ++n)
            acc[m][n] = __builtin_amdgcn_mfma_f32_16x16x32_bf16(
                aF2[m][kk], bF2[n][kk], acc[m][n], 0, 0, 0);
    }
  }

#pragma unroll
  for (int m = 0; m < 4; ++m) {
    int rbase = brow + wrow + m * 16 + (lane >> 4) * 4;
#pragma unroll
    for (int j = 0; j < 4; ++j) {
      int row = rbase + j;
      bool pass = (flags[row] == 2);
#pragma unroll
      for (int n = 0; n < 4; ++n) {
        int col = bcol + wcol + n * 16 + (lane & 15);
        float v = acc[m][n][j];
        if (pass) v += h[(size_t)row * DIM + col];
        out[(size_t)row * DIM + col] = v;
      }
    }
  }
}

extern "C" void kernel_launch(void* const* d_in, const int* in_sizes, int n_in,
                              void* d_out, int out_size, void* d_ws, size_t ws_size,
                              hipStream_t stream) {
  const float* x = (const float*)d_in[0];
  const float* h = (const float*)d_in[1];
  const float* W_ih = (const float*)d_in[2];
  const float* W_hh = (const float*)d_in[3];
  const float* W_inv = (const float*)d_in[4];
  float* out = (float*)d_out;

  char* ws = (char*)d_ws;
  int* flags = (int*)ws;                               // 64 KB
  u16* WihB = (u16*)(ws + (64 << 10));                 // 8 MB
  u16* WhhT = WihB + (size_t)DIM * DIM;                // 8 MB
  u16* WinvT = WhhT + (size_t)DIM * DIM;               // 8 MB
  u16* xb = WinvT + (size_t)DIM * DIM;                 // 64 MB
  u16* hF = xb + (size_t)B_ROWS * DIM;                 // 64 MB
  u16* hI = hF + (size_t)B_ROWS * DIM;                 // 64 MB
  size_t need = (size_t)(64 << 10) + 3ull * DIM * DIM * 2 + 3ull * B_ROWS * DIM * 2;

  k_convert<<<(DIM * DIM / 4) / 256, 256, 0, stream>>>(W_ih, WihB);
  k_transpose<<<dim3(DIM / 32, DIM / 32), 256, 0, stream>>>(W_hh, WhhT);
  k_transpose<<<dim3(DIM / 32, DIM / 32), 256, 0, stream>>>(W_inv, WinvT);

  if (ws_size >= need) {
    k_prep<<<B_ROWS / 4, 256, 0, stream>>>(x, h, W_ih, flags, xb, hF, hI);
    k_gemm8<<<(B_ROWS / 256) * (DIM / 256), 512, 0, stream>>>(
        xb, hF, hI, WihB, WhhT, WinvT, flags, h, out);
  } else {
    k_flags_fb<<<B_ROWS / 4, 256, 0, stream>>>(x, h, W_ih, flags);
    k_gemm_fb<<<(B_ROWS / BM) * (DIM / BN), 256, 0, stream>>>(x, h, WihB, WhhT,
                                                              WinvT, flags, out);
  }
}

// Round 6
// 503.237 us; speedup vs baseline: 1.5694x; 1.0064x over previous
//
#include <hip/hip_runtime.h>
#include <hip/hip_bf16.h>
#include <stdint.h>

#define B_ROWS 16384
#define DIM 2048
#define BK 64
#define NT 96        // 3 segments x 32 K-tiles

typedef float f32x4 __attribute__((ext_vector_type(4)));
typedef short bf16x8 __attribute__((ext_vector_type(8)));
using u16 = unsigned short;
using u32 = unsigned int;

__device__ __forceinline__ u32 pack_bf2(float a, float b) {
  __hip_bfloat162 t = __float22bfloat162_rn(float2{a, b});
  union { __hip_bfloat162 b2; u32 u; } cv;
  cv.b2 = t;
  return cv.u;
}

__device__ __forceinline__ u16 f2bf_rne(float f) {
  union { float f; u32 u; } v;
  v.f = f;
  u32 u = v.u;
  u32 r = u + 0x7FFFu + ((u >> 16) & 1u);
  return (u16)(r >> 16);
}

__device__ __forceinline__ void gload16(const void* g, void* l) {
  __builtin_amdgcn_global_load_lds(
      (const __attribute__((address_space(1))) u32*)g,
      (__attribute__((address_space(3))) u32*)l, 16, 0, 0);
}

// ---- prep: flags (fp64 last-col dot) + x->bf16 + masked hF/hI --------------
__global__ __launch_bounds__(256) void k_prep(
    const float* __restrict__ x, const float* __restrict__ h,
    const float* __restrict__ W_ih, int* __restrict__ flags,
    u16* __restrict__ xb, u16* __restrict__ hF, u16* __restrict__ hI) {
  int row = blockIdx.x * 4 + (threadIdx.x >> 6);
  int lane = threadIdx.x & 63;
  const float* xr = x + (size_t)row * DIM;
  const float* hr = h + (size_t)row * DIM;
  const float* wr = W_ih + (size_t)(DIM - 1) * DIM;
  u16* xbr = xb + (size_t)row * DIM;
  double s = 0.0;
  u32 hp[16];
#pragma unroll
  for (int i = 0; i < 8; ++i) {
    int idx = (i * 64 + lane) * 4;
    f32x4 xv = *(const f32x4*)(xr + idx);
    f32x4 wv = *(const f32x4*)(wr + idx);
    f32x4 hv = *(const f32x4*)(hr + idx);
    s += (double)xv.x * wv.x + (double)xv.y * wv.y +
         (double)xv.z * wv.z + (double)xv.w * wv.w;
    *(uint2*)(xbr + idx) = uint2{pack_bf2(xv.x, xv.y), pack_bf2(xv.z, xv.w)};
    hp[2 * i] = pack_bf2(hv.x, hv.y);
    hp[2 * i + 1] = pack_bf2(hv.z, hv.w);
  }
#pragma unroll
  for (int off = 32; off > 0; off >>= 1) s += __shfl_xor(s, off);
  float hl = hr[DIM - 1];
  int f = (s < -1.0) ? 2 : (hl > 0.f ? 0 : (hl < 0.f ? 1 : 3));
  if (lane == 0) flags[row] = f;
  uint2 z{0u, 0u};
  u16* hFr = hF + (size_t)row * DIM;
  u16* hIr = hI + (size_t)row * DIM;
#pragma unroll
  for (int i = 0; i < 8; ++i) {
    int idx = (i * 64 + lane) * 4;
    uint2 p{hp[2 * i], hp[2 * i + 1]};
    *(uint2*)(hFr + idx) = (f == 0) ? p : z;
    *(uint2*)(hIr + idx) = (f == 1) ? p : z;
  }
}

// ---- flags only (fallback path) --------------------------------------------
__global__ __launch_bounds__(256) void k_flags_fb(
    const float* __restrict__ x, const float* __restrict__ h,
    const float* __restrict__ W_ih, int* __restrict__ flags) {
  int row = blockIdx.x * 4 + (threadIdx.x >> 6);
  int lane = threadIdx.x & 63;
  const float* xr = x + (size_t)row * DIM;
  const float* wr = W_ih + (size_t)(DIM - 1) * DIM;
  double s = 0.0;
#pragma unroll
  for (int i = 0; i < 8; ++i) {
    int idx = (i * 64 + lane) * 4;
    f32x4 xv = *(const f32x4*)(xr + idx);
    f32x4 wv = *(const f32x4*)(wr + idx);
    s += (double)xv.x * wv.x + (double)xv.y * wv.y +
         (double)xv.z * wv.z + (double)xv.w * wv.w;
  }
#pragma unroll
  for (int off = 32; off > 0; off >>= 1) s += __shfl_xor(s, off);
  if (lane == 0) {
    float hl = h[(size_t)row * DIM + (DIM - 1)];
    flags[row] = (s < -1.0) ? 2 : (hl > 0.f ? 0 : (hl < 0.f ? 1 : 3));
  }
}

// ---- convert W_ih ([N][K] already) f32 -> bf16 ------------------------------
__global__ __launch_bounds__(256) void k_convert(const float* __restrict__ src,
                                                 u16* __restrict__ dst) {
  size_t i = ((size_t)blockIdx.x * 256 + threadIdx.x) * 4;
  f32x4 v = *(const f32x4*)(src + i);
  *(uint2*)(dst + i) = uint2{pack_bf2(v.x, v.y), pack_bf2(v.z, v.w)};
}

// ---- transpose+convert [K][N] f32 -> [N][K] bf16 ----------------------------
__global__ __launch_bounds__(256) void k_transpose(const float* __restrict__ src,
                                                   u16* __restrict__ dst) {
  __shared__ float tile[32][33];
  int k0 = blockIdx.x * 32;
  int n0 = blockIdx.y * 32;
  int tx = threadIdx.x & 31;
  int ty = threadIdx.x >> 5;
#pragma unroll
  for (int i = 0; i < 4; ++i)
    tile[ty + 8 * i][tx] = src[(size_t)(k0 + ty + 8 * i) * DIM + n0 + tx];
  __syncthreads();
#pragma unroll
  for (int i = 0; i < 4; ++i)
    dst[(size_t)(n0 + ty + 8 * i) * DIM + k0 + tx] = f2bf_rne(tile[tx][ty + 8 * i]);
}

// ---- 256^2 2-phase/K-tile pipelined GEMM (T3+T4+T5), swizzled K-half slabs --
// LDS: 2 buf x {Ak0|Bk0|Ak1|Bk1} x 16K = 128 KB.  1 barrier per phase.
// Phase kk reads both mh halves (12 ds_read_b128) + 32 MFMA.
// Stage map: kk0 stages (T+1,k1 pair)->other buf; kk1 stages (T+2,k0 pair)
// ->current buf (its k0 readers finished a barrier+MFMA cluster ago).
// vmcnt(8) per phase retires exactly the pair the NEXT phase reads (staged
// 2 phases = ~2800 cyc earlier -> never drains, full latency cover).
__global__ __launch_bounds__(512, 2) void k_gemm8(
    const u16* __restrict__ xb, const u16* __restrict__ hF,
    const u16* __restrict__ hI, const u16* __restrict__ Wih,
    const u16* __restrict__ WhhT, const u16* __restrict__ WinvT,
    const int* __restrict__ flags, const float* __restrict__ h,
    float* __restrict__ out) {
  __shared__ __attribute__((aligned(128))) char smem[131072];

  int o = blockIdx.x;
  int swz = (o & 7) * 64 + (o >> 3);     // 512 blocks, 8 XCDs, bijective
  int brow = (swz >> 3) * 256;
  int bcol = (swz & 7) * 256;

  int t = threadIdx.x;
  int lane = t & 63;
  int wave = t >> 6;
  int wr = wave >> 2;                    // 0..1  (M half)
  int wc = wave & 3;                     // 0..3  (N quarter)

  // staging source-chunk swizzle: chunk = (lane&3) ^ ((lane>>3)&3)
  int sx16 = (((lane & 3) ^ ((lane >> 3) & 3)) << 4);
  // fragment read chunk swizzle: chunk = (lane>>4) ^ ((lane>>1)&3)
  int fA = (((lane >> 4) ^ ((lane >> 1) & 3)) << 4);
  int arowbase = wr * 128 + (lane & 15);
  int browbase = wc * 64 + (lane & 15);

  auto stage = [&](int T, int isB, int kk) {
    if (T >= NT) T -= NT;
    int seg = T >> 5;
    int kt = T & 31;
    const u16* mat = isB ? (seg == 0 ? Wih : seg == 1 ? WhhT : WinvT)
                         : (seg == 0 ? xb : seg == 1 ? hF : hI);
    int r0 = isB ? bcol : brow;
    size_t gb = (size_t)(r0 + wave * 32 + (lane >> 2)) * (DIM * 2) +
                (size_t)kt * 128 + (size_t)kk * 64 + (size_t)sx16;
    char* ldst = smem + ((T & 1) << 16) + kk * 32768 + isB * 16384 +
                 (wave * 32) * 64;
    gload16((const char*)mat + gb, ldst);
    gload16((const char*)mat + gb + (size_t)16 * (DIM * 2), ldst + 1024);
  };

  f32x4 acc[8][4] = {};
  bf16x8 aF[8], bF[4];

  // prologue FIFO: [(0,k0 pair),(0,k1 pair),(1,k0 pair)]; retire (0,k0).
  stage(0, 0, 0); stage(0, 1, 0);
  stage(0, 0, 1); stage(0, 1, 1);
  stage(1, 0, 0); stage(1, 1, 0);
  asm volatile("s_waitcnt vmcnt(8)" ::: "memory");
  __builtin_amdgcn_s_barrier();

#define PHASE(KK, STT, STKK)                                                   \
  {                                                                            \
    const char* Ab_ = smem + buf + (KK) * 32768;                               \
    _Pragma("unroll") for (int m = 0; m < 4; ++m) {                            \
      aF[m] = *(const bf16x8*)(Ab_ + (arowbase + m * 16) * 64 + fA);           \
      aF[4 + m] = *(const bf16x8*)(Ab_ + (arowbase + 64 + m * 16) * 64 + fA);  \
    }                                                                          \
    _Pragma("unroll") for (int n = 0; n < 4; ++n)                              \
        bF[n] = *(const bf16x8*)(Ab_ + 16384 + (browbase + n * 16) * 64 + fA); \
    stage(STT, 0, STKK);                                                       \
    stage(STT, 1, STKK);                                                       \
    asm volatile("s_waitcnt vmcnt(8)" ::: "memory");                           \
    __builtin_amdgcn_s_barrier();                                              \
    asm volatile("s_waitcnt lgkmcnt(0)" ::: "memory");                         \
    __builtin_amdgcn_sched_barrier(0);                                         \
    __builtin_amdgcn_s_setprio(1);                                             \
    _Pragma("unroll") for (int mh = 0; mh < 2; ++mh)                           \
        _Pragma("unroll") for (int m = 0; m < 4; ++m)                          \
            _Pragma("unroll") for (int n = 0; n < 4; ++n)                      \
                acc[mh * 4 + m][n] = __builtin_amdgcn_mfma_f32_16x16x32_bf16(  \
                    aF[mh * 4 + m], bF[n], acc[mh * 4 + m][n], 0, 0, 0);       \
    __builtin_amdgcn_s_setprio(0);                                             \
  }

#pragma unroll 1
  for (int T = 0; T < NT; ++T) {
    const int buf = (T & 1) << 16;
    PHASE(0, T + 1, 1)   // read k0 (both mh) + 32 MFMA; stage (T+1) k1 pair
    PHASE(1, T + 2, 0)   // read k1 (both mh) + 32 MFMA; stage (T+2) k0 pair
  }
#undef PHASE
  asm volatile("s_waitcnt vmcnt(0)" ::: "memory");

  // epilogue: C mapping col=lane&15, row=(lane>>4)*4+j (R2-proven layout)
#pragma unroll
  for (int mi = 0; mi < 8; ++mi) {
    int rbase = brow + wr * 128 + (mi >> 2) * 64 + (mi & 3) * 16 + (lane >> 4) * 4;
#pragma unroll
    for (int j = 0; j < 4; ++j) {
      int row = rbase + j;
      bool pass = (flags[row] == 2);
#pragma unroll
      for (int n = 0; n < 4; ++n) {
        int col = bcol + wc * 64 + n * 16 + (lane & 15);
        float v = acc[mi][n][j];
        if (pass) v += h[(size_t)row * DIM + col];
        out[(size_t)row * DIM + col] = v;
      }
    }
  }
}

// ---- fallback (ws too small): R1 reg-staged 3-segment masked GEMM -----------
#define BM 128
#define BN 128
__global__ __launch_bounds__(256, 2) void k_gemm_fb(
    const float* __restrict__ x, const float* __restrict__ h,
    const u16* __restrict__ Wih, const u16* __restrict__ WhhT,
    const u16* __restrict__ WinvT, const int* __restrict__ flags,
    float* __restrict__ out) {
  __shared__ char smem[(BM + BN) * BK * 2];
  char* sA = smem;
  char* sB = smem + BM * BK * 2;

  int o = blockIdx.x;
  int swz = (o & 7) * ((int)gridDim.x >> 3) + (o >> 3);
  int brow = (swz >> 4) * BM;
  int bcol = (swz & 15) * BN;

  int t = threadIdx.x;
  int lane = t & 63;
  int wave = t >> 6;
  int wrow = (wave >> 1) * 64;
  int wcol = (wave & 1) * 64;

  f32x4 acc[4][4] = {};
  int sc = t & 15;
  int sr0 = t >> 4;

  int aOff[4][2], bOff[4][2];
#pragma unroll
  for (int m = 0; m < 4; ++m)
#pragma unroll
    for (int kk = 0; kk < 2; ++kk) {
      int ar = wrow + m * 16 + (lane & 15);
      aOff[m][kk] = ar * (BK * 2) + ((kk * 64 + (lane >> 4) * 16) ^ ((ar & 7) << 4));
      int br = wcol + m * 16 + (lane & 15);
      bOff[m][kk] = br * (BK * 2) + ((kk * 64 + (lane >> 4) * 16) ^ ((br & 7) << 4));
    }

#pragma unroll 1
  for (int seg = 0; seg < 3; ++seg) {
    const float* Asrc = (seg == 0) ? x : h;
    const u16* Bsrc = (seg == 0) ? Wih : (seg == 1) ? WhhT : WinvT;
    int want = seg - 1;

    float rmask[8];
#pragma unroll
    for (int i = 0; i < 8; ++i) {
      int r = sr0 + 16 * i;
      rmask[i] = (want < 0 || flags[brow + r] == want) ? 1.f : 0.f;
    }

#pragma unroll 1
    for (int k0 = 0; k0 < DIM; k0 += BK) {
      __syncthreads();
#pragma unroll
      for (int i = 0; i < 8; ++i) {
        int r = sr0 + 16 * i;
        f32x4 v = *(const f32x4*)(Asrc + (size_t)(brow + r) * DIM + k0 + sc * 4);
        float msk = rmask[i];
        int off = r * (BK * 2) + ((sc * 8) ^ ((r & 7) << 4));
        *(uint2*)(sA + off) =
            uint2{pack_bf2(v.x * msk, v.y * msk), pack_bf2(v.z * msk, v.w * msk)};
      }
#pragma unroll
      for (int i = 0; i < 4; ++i) {
        int ch = t + 256 * i;
        int r = ch >> 3;
        int c = ch & 7;
        uint4 v = *(const uint4*)(Bsrc + (size_t)(bcol + r) * DIM + k0 + c * 8);
        int off = r * (BK * 2) + ((c * 16) ^ ((r & 7) << 4));
        *(uint4*)(sB + off) = v;
      }
      __syncthreads();
      bf16x8 aF2[4][2], bF2[4][2];
#pragma unroll
      for (int m = 0; m < 4; ++m)
#pragma unroll
        for (int kk = 0; kk < 2; ++kk) {
          aF2[m][kk] = *(const bf16x8*)(sA + aOff[m][kk]);
          bF2[m][kk] = *(const bf16x8*)(sB + bOff[m][kk]);
        }
#pragma unroll
      for (int kk = 0; kk < 2; ++kk)
#pragma unroll
        for (int m = 0; m < 4; ++m)
#pragma unroll
          for (int n = 0; n < 4; ++n)
            acc[m][n] = __builtin_amdgcn_mfma_f32_16x16x32_bf16(
                aF2[m][kk], bF2[n][kk], acc[m][n], 0, 0, 0);
    }
  }

#pragma unroll
  for (int m = 0; m < 4; ++m) {
    int rbase = brow + wrow + m * 16 + (lane >> 4) * 4;
#pragma unroll
    for (int j = 0; j < 4; ++j) {
      int row = rbase + j;
      bool pass = (flags[row] == 2);
#pragma unroll
      for (int n = 0; n < 4; ++n) {
        int col = bcol + wcol + n * 16 + (lane & 15);
        float v = acc[m][n][j];
        if (pass) v += h[(size_t)row * DIM + col];
        out[(size_t)row * DIM + col] = v;
      }
    }
  }
}

extern "C" void kernel_launch(void* const* d_in, const int* in_sizes, int n_in,
                              void* d_out, int out_size, void* d_ws, size_t ws_size,
                              hipStream_t stream) {
  const float* x = (const float*)d_in[0];
  const float* h = (const float*)d_in[1];
  const float* W_ih = (const float*)d_in[2];
  const float* W_hh = (const float*)d_in[3];
  const float* W_inv = (const float*)d_in[4];
  float* out = (float*)d_out;

  char* ws = (char*)d_ws;
  int* flags = (int*)ws;                               // 64 KB
  u16* WihB = (u16*)(ws + (64 << 10));                 // 8 MB
  u16* WhhT = WihB + (size_t)DIM * DIM;                // 8 MB
  u16* WinvT = WhhT + (size_t)DIM * DIM;               // 8 MB
  u16* xb = WinvT + (size_t)DIM * DIM;                 // 64 MB
  u16* hF = xb + (size_t)B_ROWS * DIM;                 // 64 MB
  u16* hI = hF + (size_t)B_ROWS * DIM;                 // 64 MB
  size_t need = (size_t)(64 << 10) + 3ull * DIM * DIM * 2 + 3ull * B_ROWS * DIM * 2;

  k_convert<<<(DIM * DIM / 4) / 256, 256, 0, stream>>>(W_ih, WihB);
  k_transpose<<<dim3(DIM / 32, DIM / 32), 256, 0, stream>>>(W_hh, WhhT);
  k_transpose<<<dim3(DIM / 32, DIM / 32), 256, 0, stream>>>(W_inv, WinvT);

  if (ws_size >= need) {
    k_prep<<<B_ROWS / 4, 256, 0, stream>>>(x, h, W_ih, flags, xb, hF, hI);
    k_gemm8<<<(B_ROWS / 256) * (DIM / 256), 512, 0, stream>>>(
        xb, hF, hI, WihB, WhhT, WinvT, flags, h, out);
  } else {
    k_flags_fb<<<B_ROWS / 4, 256, 0, stream>>>(x, h, W_ih, flags);
    k_gemm_fb<<<(B_ROWS / BM) * (DIM / BN), 256, 0, stream>>>(x, h, WihB, WhhT,
                                                              WinvT, flags, out);
  }
}